// Round 1
// baseline (1101.606 us; speedup 1.0000x reference)
//
#include <hip/hip_runtime.h>
#include <hip/hip_bf16.h>
#include <math.h>

// ---- problem constants ----
#define NT     100352   // B*H*W tokens (= 2048 windows * 49)
#define NWIN   2048     // B * nW
#define NN     49       // tokens per window
#define CH     128
#define NHEADS 4
#define HD     32
#define MLPD   512
#define SHIFT  3
#define IMG    56
#define SCALE_Q 0.17677669529663687f

typedef unsigned short u16;
typedef unsigned int   u32;

__device__ __forceinline__ float b2f(u16 h) {
    u32 u = ((u32)h) << 16;
    return __uint_as_float(u);
}
__device__ __forceinline__ u16 f2b(float f) {   // round-to-nearest-even
    u32 u = __float_as_uint(f);
    u32 r = (u + 0x7fffu + ((u >> 16) & 1u)) >> 16;
    return (u16)r;
}

// ---------------------------------------------------------------
// LN (+ optional roll & window partition) -> bf16
// block = 256 = 4 waves, one token per wave; lane handles c and c+64
// ---------------------------------------------------------------
__global__ __launch_bounds__(256) void k_ln(const float* __restrict__ x,
                                            const float* __restrict__ g,
                                            const float* __restrict__ bta,
                                            u16* __restrict__ out, int rolled)
{
    int wave = threadIdx.x >> 6;
    int lane = threadIdx.x & 63;
    int t = blockIdx.x * 4 + wave;
    if (t >= NT) return;
    int src;
    if (rolled) {
        int w = t / NN, n = t % NN;
        int bb = w >> 6, iw = w & 63;
        int wh = iw >> 3, ww = iw & 7;
        int i = n / 7, j = n % 7;
        int hs = (wh * 7 + i + SHIFT) % IMG;
        int wsd = (ww * 7 + j + SHIFT) % IMG;
        src = bb * 3136 + hs * 56 + wsd;
    } else {
        src = t;
    }
    float v0 = x[(size_t)src * CH + lane];
    float v1 = x[(size_t)src * CH + 64 + lane];
    float s = v0 + v1;
    #pragma unroll
    for (int o = 32; o; o >>= 1) s += __shfl_xor(s, o);
    float mu = s * (1.0f / 128.0f);
    float d0 = v0 - mu, d1 = v1 - mu;
    float vs = d0 * d0 + d1 * d1;
    #pragma unroll
    for (int o = 32; o; o >>= 1) vs += __shfl_xor(vs, o);
    float rs = rsqrtf(vs * (1.0f / 128.0f) + 1e-5f);
    out[(size_t)t * CH + lane]      = f2b(d0 * rs * g[lane] + bta[lane]);
    out[(size_t)t * CH + 64 + lane] = f2b(d1 * rs * g[64 + lane] + bta[64 + lane]);
}

// ---------------------------------------------------------------
// QKV GEMM: [NT,128] @ [128,384] + b  -> q(scaled)/k/v  [win][head][n][d] bf16
// tile 64x64, K=128, 256 thr, 4x4 per thread
// ---------------------------------------------------------------
__global__ __launch_bounds__(256) void k_qkv(const u16* __restrict__ A,
                                             const float* __restrict__ W,
                                             const float* __restrict__ bias,
                                             u16* __restrict__ q,
                                             u16* __restrict__ kk,
                                             u16* __restrict__ vv)
{
    __shared__ u16 As[64][136];
    __shared__ u16 Bs[128][64];
    int rt = blockIdx.x / 6, ct = blockIdx.x % 6;
    int row0 = rt * 64, c0t = ct * 64;
    int tid = threadIdx.x;
    for (int idx = tid; idx < 64 * 128; idx += 256) {
        int r = idx >> 7, k = idx & 127;
        As[r][k] = A[(size_t)(row0 + r) * CH + k];
    }
    for (int idx = tid; idx < 128 * 64; idx += 256) {
        int k = idx >> 6, c = idx & 63;
        Bs[k][c] = f2b(W[k * 384 + c0t + c]);
    }
    __syncthreads();
    int tx = tid & 15, ty = tid >> 4;
    float acc[4][4] = {};
    #pragma unroll 4
    for (int k = 0; k < 128; ++k) {
        float a0 = b2f(As[ty * 4 + 0][k]);
        float a1 = b2f(As[ty * 4 + 1][k]);
        float a2 = b2f(As[ty * 4 + 2][k]);
        float a3 = b2f(As[ty * 4 + 3][k]);
        short4 bv = *(const short4*)&Bs[k][tx * 4];
        float b0 = b2f((u16)bv.x), b1 = b2f((u16)bv.y);
        float b2 = b2f((u16)bv.z), b3 = b2f((u16)bv.w);
        acc[0][0] += a0 * b0; acc[0][1] += a0 * b1; acc[0][2] += a0 * b2; acc[0][3] += a0 * b3;
        acc[1][0] += a1 * b0; acc[1][1] += a1 * b1; acc[1][2] += a1 * b2; acc[1][3] += a1 * b3;
        acc[2][0] += a2 * b0; acc[2][1] += a2 * b1; acc[2][2] += a2 * b2; acc[2][3] += a2 * b3;
        acc[3][0] += a3 * b0; acc[3][1] += a3 * b1; acc[3][2] += a3 * b2; acc[3][3] += a3 * b3;
    }
    #pragma unroll
    for (int rr = 0; rr < 4; ++rr) {
        int t = row0 + ty * 4 + rr;
        int w = t / NN, n = t % NN;
        #pragma unroll
        for (int cc = 0; cc < 4; ++cc) {
            int col = c0t + tx * 4 + cc;
            float v = acc[rr][cc] + bias[col];
            int part = col >> 7;
            int within = col & 127;
            int head = within >> 5, d = within & 31;
            size_t idx = ((size_t)(w * NHEADS + head) * NN + n) * HD + d;
            if (part == 0)      q[idx]  = f2b(v * SCALE_Q);
            else if (part == 1) kk[idx] = f2b(v);
            else                vv[idx] = f2b(v);
        }
    }
}

// ---------------------------------------------------------------
// Attention: one block per (window, head). bias + shift mask computed inline.
// ---------------------------------------------------------------
__global__ __launch_bounds__(256) void k_attn(const u16* __restrict__ q,
                                              const u16* __restrict__ kk,
                                              const u16* __restrict__ vv,
                                              const float* __restrict__ relt,
                                              u16* __restrict__ owin)
{
    __shared__ float Q[NN][HD], K[NN][HD], V[NN][HD];
    __shared__ float S[NN][NN];
    int w = blockIdx.x >> 2, head = blockIdx.x & 3;
    size_t base = (size_t)(w * NHEADS + head) * NN * HD;
    int tid = threadIdx.x;
    for (int i = tid; i < NN * HD; i += 256) {
        ((float*)Q)[i] = b2f(q[base + i]);
        ((float*)K)[i] = b2f(kk[base + i]);
        ((float*)V)[i] = b2f(vv[base + i]);
    }
    __syncthreads();
    int iw = w & 63;
    int wh = iw >> 3, ww = iw & 7;
    for (int e = tid; e < NN * NN; e += 256) {
        int n = e / NN, m = e % NN;
        float acc = 0.f;
        #pragma unroll
        for (int d = 0; d < HD; ++d) acc += Q[n][d] * K[m][d];
        int in_ = n / 7, jn = n % 7, im = m / 7, jm = m % 7;
        int ridx = (in_ - im + 6) * 13 + (jn - jm + 6);
        acc += relt[ridx * NHEADS + head];
        int hn = wh * 7 + in_, wn = ww * 7 + jn;
        int hm = wh * 7 + im, wm = ww * 7 + jm;
        int zn = (hn < 49 ? 0 : (hn < 53 ? 1 : 2)) * 3 + (wn < 49 ? 0 : (wn < 53 ? 1 : 2));
        int zm = (hm < 49 ? 0 : (hm < 53 ? 1 : 2)) * 3 + (wm < 49 ? 0 : (wm < 53 ? 1 : 2));
        if (zn != zm) acc -= 100.0f;
        ((float*)S)[e] = acc;
    }
    __syncthreads();
    if (tid < NN) {
        float mx = -1e30f;
        #pragma unroll 7
        for (int m = 0; m < NN; ++m) mx = fmaxf(mx, S[tid][m]);
        float sum = 0.f;
        #pragma unroll 7
        for (int m = 0; m < NN; ++m) { float e_ = __expf(S[tid][m] - mx); S[tid][m] = e_; sum += e_; }
        float inv = 1.0f / sum;
        #pragma unroll 7
        for (int m = 0; m < NN; ++m) S[tid][m] *= inv;
    }
    __syncthreads();
    for (int e = tid; e < NN * HD; e += 256) {
        int n = e >> 5, d = e & 31;
        float acc = 0.f;
        #pragma unroll 7
        for (int m = 0; m < NN; ++m) acc += S[n][m] * V[m][d];
        owin[(size_t)(w * NN + n) * CH + head * HD + d] = f2b(acc);
    }
}

// ---------------------------------------------------------------
// Proj GEMM [NT,128]@[128,128] + bias, window-reverse + roll(+3) + skip-add
// writes x1 (f32) into d_out
// ---------------------------------------------------------------
__global__ __launch_bounds__(256) void k_proj(const u16* __restrict__ A,
                                              const float* __restrict__ W,
                                              const float* __restrict__ bias,
                                              const float* __restrict__ xin,
                                              float* __restrict__ out)
{
    __shared__ u16 As[64][136];
    __shared__ u16 Bs[128][64];
    int rt = blockIdx.x >> 1, ct = blockIdx.x & 1;
    int row0 = rt * 64, c0t = ct * 64;
    int tid = threadIdx.x;
    for (int idx = tid; idx < 64 * 128; idx += 256) {
        int r = idx >> 7, k = idx & 127;
        As[r][k] = A[(size_t)(row0 + r) * CH + k];
    }
    for (int idx = tid; idx < 128 * 64; idx += 256) {
        int k = idx >> 6, c = idx & 63;
        Bs[k][c] = f2b(W[k * CH + c0t + c]);
    }
    __syncthreads();
    int tx = tid & 15, ty = tid >> 4;
    float acc[4][4] = {};
    #pragma unroll 4
    for (int k = 0; k < 128; ++k) {
        float a0 = b2f(As[ty * 4 + 0][k]);
        float a1 = b2f(As[ty * 4 + 1][k]);
        float a2 = b2f(As[ty * 4 + 2][k]);
        float a3 = b2f(As[ty * 4 + 3][k]);
        short4 bv = *(const short4*)&Bs[k][tx * 4];
        float b0 = b2f((u16)bv.x), b1 = b2f((u16)bv.y);
        float b2 = b2f((u16)bv.z), b3 = b2f((u16)bv.w);
        acc[0][0] += a0 * b0; acc[0][1] += a0 * b1; acc[0][2] += a0 * b2; acc[0][3] += a0 * b3;
        acc[1][0] += a1 * b0; acc[1][1] += a1 * b1; acc[1][2] += a1 * b2; acc[1][3] += a1 * b3;
        acc[2][0] += a2 * b0; acc[2][1] += a2 * b1; acc[2][2] += a2 * b2; acc[2][3] += a2 * b3;
        acc[3][0] += a3 * b0; acc[3][1] += a3 * b1; acc[3][2] += a3 * b2; acc[3][3] += a3 * b3;
    }
    #pragma unroll
    for (int rr = 0; rr < 4; ++rr) {
        int t = row0 + ty * 4 + rr;
        int w = t / NN, n = t % NN;
        int bb = w >> 6, iw = w & 63;
        int wh = iw >> 3, wwn = iw & 7;
        int i = n / 7, j = n % 7;
        int dh = (wh * 7 + i + SHIFT) % IMG;
        int dw = (wwn * 7 + j + SHIFT) % IMG;
        size_t dst = (size_t)bb * 3136 + dh * 56 + dw;
        #pragma unroll
        for (int cc = 0; cc < 4; ++cc) {
            int col = c0t + tx * 4 + cc;
            out[dst * CH + col] = xin[dst * CH + col] + acc[rr][cc] + bias[col];
        }
    }
}

// ---------------------------------------------------------------
// FC1 GEMM [NT,128]@[128,512] + bias + exact GELU -> m1 bf16
// ---------------------------------------------------------------
__global__ __launch_bounds__(256) void k_fc1(const u16* __restrict__ A,
                                             const float* __restrict__ W,
                                             const float* __restrict__ bias,
                                             u16* __restrict__ m1)
{
    __shared__ u16 As[64][136];
    __shared__ u16 Bs[128][64];
    int rt = blockIdx.x >> 3, ct = blockIdx.x & 7;
    int row0 = rt * 64, c0t = ct * 64;
    int tid = threadIdx.x;
    for (int idx = tid; idx < 64 * 128; idx += 256) {
        int r = idx >> 7, k = idx & 127;
        As[r][k] = A[(size_t)(row0 + r) * CH + k];
    }
    for (int idx = tid; idx < 128 * 64; idx += 256) {
        int k = idx >> 6, c = idx & 63;
        Bs[k][c] = f2b(W[k * MLPD + c0t + c]);
    }
    __syncthreads();
    int tx = tid & 15, ty = tid >> 4;
    float acc[4][4] = {};
    #pragma unroll 4
    for (int k = 0; k < 128; ++k) {
        float a0 = b2f(As[ty * 4 + 0][k]);
        float a1 = b2f(As[ty * 4 + 1][k]);
        float a2 = b2f(As[ty * 4 + 2][k]);
        float a3 = b2f(As[ty * 4 + 3][k]);
        short4 bv = *(const short4*)&Bs[k][tx * 4];
        float b0 = b2f((u16)bv.x), b1 = b2f((u16)bv.y);
        float b2 = b2f((u16)bv.z), b3 = b2f((u16)bv.w);
        acc[0][0] += a0 * b0; acc[0][1] += a0 * b1; acc[0][2] += a0 * b2; acc[0][3] += a0 * b3;
        acc[1][0] += a1 * b0; acc[1][1] += a1 * b1; acc[1][2] += a1 * b2; acc[1][3] += a1 * b3;
        acc[2][0] += a2 * b0; acc[2][1] += a2 * b1; acc[2][2] += a2 * b2; acc[2][3] += a2 * b3;
        acc[3][0] += a3 * b0; acc[3][1] += a3 * b1; acc[3][2] += a3 * b2; acc[3][3] += a3 * b3;
    }
    #pragma unroll
    for (int rr = 0; rr < 4; ++rr) {
        int t = row0 + ty * 4 + rr;
        #pragma unroll
        for (int cc = 0; cc < 4; ++cc) {
            int col = c0t + tx * 4 + cc;
            float v = acc[rr][cc] + bias[col];
            float gv = 0.5f * v * (1.0f + erff(v * 0.70710678118654752f));
            m1[(size_t)t * MLPD + col] = f2b(gv);
        }
    }
}

// ---------------------------------------------------------------
// FC2 GEMM [NT,512]@[512,128] + bias + in-place skip add into d_out
// K = 512 in 4 chunks of 128
// ---------------------------------------------------------------
__global__ __launch_bounds__(256) void k_fc2(const u16* __restrict__ A,
                                             const float* __restrict__ W,
                                             const float* __restrict__ bias,
                                             float* __restrict__ out)
{
    __shared__ u16 As[64][136];
    __shared__ u16 Bs[128][64];
    int rt = blockIdx.x >> 1, ct = blockIdx.x & 1;
    int row0 = rt * 64, c0t = ct * 64;
    int tid = threadIdx.x;
    int tx = tid & 15, ty = tid >> 4;
    float acc[4][4] = {};
    for (int kc = 0; kc < 4; ++kc) {
        for (int idx = tid; idx < 64 * 128; idx += 256) {
            int r = idx >> 7, k = idx & 127;
            As[r][k] = A[(size_t)(row0 + r) * MLPD + kc * 128 + k];
        }
        for (int idx = tid; idx < 128 * 64; idx += 256) {
            int k = idx >> 6, c = idx & 63;
            Bs[k][c] = f2b(W[(kc * 128 + k) * CH + c0t + c]);
        }
        __syncthreads();
        #pragma unroll 4
        for (int k = 0; k < 128; ++k) {
            float a0 = b2f(As[ty * 4 + 0][k]);
            float a1 = b2f(As[ty * 4 + 1][k]);
            float a2 = b2f(As[ty * 4 + 2][k]);
            float a3 = b2f(As[ty * 4 + 3][k]);
            short4 bv = *(const short4*)&Bs[k][tx * 4];
            float b0 = b2f((u16)bv.x), b1 = b2f((u16)bv.y);
            float b2 = b2f((u16)bv.z), b3 = b2f((u16)bv.w);
            acc[0][0] += a0 * b0; acc[0][1] += a0 * b1; acc[0][2] += a0 * b2; acc[0][3] += a0 * b3;
            acc[1][0] += a1 * b0; acc[1][1] += a1 * b1; acc[1][2] += a1 * b2; acc[1][3] += a1 * b3;
            acc[2][0] += a2 * b0; acc[2][1] += a2 * b1; acc[2][2] += a2 * b2; acc[2][3] += a2 * b3;
            acc[3][0] += a3 * b0; acc[3][1] += a3 * b1; acc[3][2] += a3 * b2; acc[3][3] += a3 * b3;
        }
        __syncthreads();
    }
    #pragma unroll
    for (int rr = 0; rr < 4; ++rr) {
        int t = row0 + ty * 4 + rr;
        #pragma unroll
        for (int cc = 0; cc < 4; ++cc) {
            int col = c0t + tx * 4 + cc;
            size_t oidx = (size_t)t * CH + col;
            out[oidx] = out[oidx] + acc[rr][cc] + bias[col];
        }
    }
}

// ---------------------------------------------------------------
extern "C" void kernel_launch(void* const* d_in, const int* in_sizes, int n_in,
                              void* d_out, int out_size, void* d_ws, size_t ws_size,
                              hipStream_t stream) {
    const float* x       = (const float*)d_in[0];
    const float* qkv_w   = (const float*)d_in[1];
    const float* qkv_b   = (const float*)d_in[2];
    const float* proj_w  = (const float*)d_in[3];
    const float* proj_b  = (const float*)d_in[4];
    const float* rel_t   = (const float*)d_in[5];
    const float* n1g     = (const float*)d_in[6];
    const float* n1b     = (const float*)d_in[7];
    const float* n2g     = (const float*)d_in[8];
    const float* n2b     = (const float*)d_in[9];
    const float* fc1_w   = (const float*)d_in[10];
    const float* fc1_b   = (const float*)d_in[11];
    const float* fc2_w   = (const float*)d_in[12];
    const float* fc2_b   = (const float*)d_in[13];
    float* out = (float*)d_out;

    const size_t REG = (size_t)NT * CH;     // elements per bf16 region
    u16* hwin = (u16*)d_ws;                 // [NT][128]
    u16* qb   = hwin + REG;                 // [2048][4][49][32]
    u16* kb   = qb + REG;
    u16* vb   = kb + REG;
    u16* owin = vb + REG;                   // [NT][128]
    u16* ln2  = hwin;                       // reuse (hwin dead after k_qkv)
    u16* m1   = qb;                         // reuse q..owin span: NT*512 bf16

    // 1. LN1 + roll + window partition
    k_ln<<<NT / 4, 256, 0, stream>>>(x, n1g, n1b, hwin, 1);
    // 2. QKV
    k_qkv<<<(NT / 64) * 6, 256, 0, stream>>>(hwin, qkv_w, qkv_b, qb, kb, vb);
    // 3. attention
    k_attn<<<NWIN * NHEADS, 256, 0, stream>>>(qb, kb, vb, rel_t, owin);
    // 4. proj + reverse + roll + skip  -> d_out = x1
    k_proj<<<(NT / 64) * 2, 256, 0, stream>>>(owin, proj_w, proj_b, x, out);
    // 5. LN2 on x1
    k_ln<<<NT / 4, 256, 0, stream>>>(out, n2g, n2b, ln2, 0);
    // 6. FC1 + GELU
    k_fc1<<<(NT / 64) * 8, 256, 0, stream>>>(ln2, fc1_w, fc1_b, m1);
    // 7. FC2 + skip (in place on d_out)
    k_fc2<<<(NT / 64) * 2, 256, 0, stream>>>(m1, fc2_w, fc2_b, out);
}

// Round 6
// 552.207 us; speedup vs baseline: 1.9949x; 1.9949x over previous
//
#include <hip/hip_runtime.h>
#include <hip/hip_bf16.h>
#include <math.h>

#define NT     100352
#define NWIN   2048
#define NN     49
#define CH     128
#define NHEADS 4
#define HD     32
#define MLPD   512
#define SHIFT  3
#define IMG    56
#define SCALE_Q 0.17677669529663687f

typedef unsigned short u16;
typedef unsigned int   u32;
typedef __attribute__((ext_vector_type(8))) short sh8;
typedef __attribute__((ext_vector_type(4))) float f32x4;

__device__ __forceinline__ float b2f(u16 h) {
    u32 u = ((u32)h) << 16;
    return __uint_as_float(u);
}
__device__ __forceinline__ u16 f2b(float f) {
    u32 u = __float_as_uint(f);
    u32 r = (u + 0x7fffu + ((u >> 16) & 1u)) >> 16;
    return (u16)r;
}

// ---------------------------------------------------------------
// weight prep: f32 [K][N] -> bf16 [N][K] (transposed), all 4 mats
// wt layout: qkvT [384][128] @0 ; projT [128][128] @49152 ;
//            fc1T [512][128] @65536 ; fc2T [128][512] @131072
// ---------------------------------------------------------------
__global__ __launch_bounds__(256) void k_prep(const float* __restrict__ qkv_w,
                                              const float* __restrict__ proj_w,
                                              const float* __restrict__ fc1_w,
                                              const float* __restrict__ fc2_w,
                                              u16* __restrict__ wt)
{
    int i = blockIdx.x * 256 + threadIdx.x;
    if (i < 49152)       { int n = i >> 7, k = i & 127;             wt[i] = f2b(qkv_w[k * 384 + n]); }
    else if (i < 65536)  { int j = i - 49152; int n = j >> 7, k = j & 127; wt[i] = f2b(proj_w[k * 128 + n]); }
    else if (i < 131072) { int j = i - 65536; int n = j >> 7, k = j & 127; wt[i] = f2b(fc1_w[k * 512 + n]); }
    else                 { int j = i - 131072; int n = j >> 9, k = j & 511; wt[i] = f2b(fc2_w[k * 128 + n]); }
}

// ---------------------------------------------------------------
// LN (+ optional roll & window partition) -> bf16
// ---------------------------------------------------------------
__global__ __launch_bounds__(256) void k_ln(const float* __restrict__ x,
                                            const float* __restrict__ g,
                                            const float* __restrict__ bta,
                                            u16* __restrict__ out, int rolled)
{
    int wave = threadIdx.x >> 6;
    int lane = threadIdx.x & 63;
    int t = blockIdx.x * 4 + wave;
    if (t >= NT) return;
    int src;
    if (rolled) {
        int w = t / NN, n = t % NN;
        int bb = w >> 6, iw = w & 63;
        int wh = iw >> 3, ww = iw & 7;
        int i = n / 7, j = n % 7;
        int hs = (wh * 7 + i + SHIFT) % IMG;
        int wsd = (ww * 7 + j + SHIFT) % IMG;
        src = bb * 3136 + hs * 56 + wsd;
    } else {
        src = t;
    }
    float v0 = x[(size_t)src * CH + lane];
    float v1 = x[(size_t)src * CH + 64 + lane];
    float s = v0 + v1;
    #pragma unroll
    for (int o = 32; o; o >>= 1) s += __shfl_xor(s, o);
    float mu = s * (1.0f / 128.0f);
    float d0 = v0 - mu, d1 = v1 - mu;
    float vs = d0 * d0 + d1 * d1;
    #pragma unroll
    for (int o = 32; o; o >>= 1) vs += __shfl_xor(vs, o);
    float rs = rsqrtf(vs * (1.0f / 128.0f) + 1e-5f);
    out[(size_t)t * CH + lane]      = f2b(d0 * rs * g[lane] + bta[lane]);
    out[(size_t)t * CH + 64 + lane] = f2b(d1 * rs * g[64 + lane] + bta[64 + lane]);
}

// ---------------------------------------------------------------
// MFMA GEMM core: 128x128 tile, BK=128, 4 waves (64x64 each),
// 4x4 frags of 16x16x32. LDS tiles XOR-swizzled (pre-swizzled global
// source via global_load_lds + swizzled ds_read — both-sides).
// ---------------------------------------------------------------
__device__ __forceinline__ void stage_tile(const u16* g, size_t krow_bytes, char* lds, int tid)
{
    #pragma unroll
    for (int it = 0; it < 8; ++it) {
        int o = (tid + it * 256) * 16;          // linear LDS byte offset
        int row = o >> 8;                       // 256B logical rows
        int wi = (o & 255) ^ ((row & 7) << 4);  // inverse-swizzled source
        const char* src = (const char*)g + (size_t)row * krow_bytes + wi;
        __builtin_amdgcn_global_load_lds((const __attribute__((address_space(1))) u32*)src,
                                         (__attribute__((address_space(3))) u32*)(lds + o),
                                         16, 0, 0);
    }
}

__device__ __forceinline__ void compute_ktile(const char* pA, const char* pB, f32x4 acc[4][4], int tid)
{
    int lane = tid & 63;
    int wv = tid >> 6;
    int wrow = (wv >> 1) * 64, wcol = (wv & 1) * 64;
    int lr = lane & 15, lk = lane >> 4;
    int xm = (lr & 7) << 4;                     // row&7 == lr&7 (frag rows 16-aligned)
    #pragma unroll
    for (int ks = 0; ks < 4; ++ks) {
        int kb = ks * 64 + lk * 16;
        sh8 a[4], b[4];
        #pragma unroll
        for (int m = 0; m < 4; ++m) {
            int ra = wrow + m * 16 + lr;
            a[m] = *(const sh8*)(pA + ra * 256 + (kb ^ xm));
        }
        #pragma unroll
        for (int n = 0; n < 4; ++n) {
            int rb = wcol + n * 16 + lr;
            b[n] = *(const sh8*)(pB + rb * 256 + (kb ^ xm));
        }
        #pragma unroll
        for (int m = 0; m < 4; ++m)
            #pragma unroll
            for (int n = 0; n < 4; ++n)
                acc[m][n] = __builtin_amdgcn_mfma_f32_16x16x32_bf16(a[m], b[n], acc[m][n], 0, 0, 0);
    }
}

#define GEMM_PROLOGUE                                           \
    int tid = threadIdx.x;                                      \
    int lane = tid & 63, wv = tid >> 6;                         \
    int wrow = (wv >> 1) * 64, wcol = (wv & 1) * 64;            \
    int lr = lane & 15, lk = lane >> 4;                         \
    f32x4 acc[4][4];                                            \
    _Pragma("unroll")                                           \
    for (int m = 0; m < 4; ++m)                                 \
        _Pragma("unroll")                                       \
        for (int n = 0; n < 4; ++n)                             \
            acc[m][n] = (f32x4){0.f, 0.f, 0.f, 0.f};

// qkv: A [NT][128] bf16, B = qkvT [384][128] bf16, out q/k/v [t][head*32+d]
__global__ __launch_bounds__(256) void k_gqkv(const u16* __restrict__ A,
                                              const u16* __restrict__ WT,
                                              const float* __restrict__ bias_all,
                                              u16* __restrict__ qb,
                                              u16* __restrict__ kb,
                                              u16* __restrict__ vb)
{
    __shared__ __align__(16) char smem[65536];
    GEMM_PROLOGUE
    int mt = blockIdx.x / 3, nt = blockIdx.x % 3;
    int row0 = mt * 128;
    stage_tile(A + (size_t)row0 * CH, CH * 2, smem, tid);
    stage_tile(WT + (size_t)nt * 128 * CH, CH * 2, smem + 32768, tid);
    __syncthreads();
    compute_ktile(smem, smem + 32768, acc, tid);
    const float* bias = bias_all + nt * 128;
    u16* dst = nt == 0 ? qb : (nt == 1 ? kb : vb);
    float scale = nt == 0 ? SCALE_Q : 1.0f;
    int rbase = row0 + wrow + lk * 4;
    #pragma unroll
    for (int m = 0; m < 4; ++m)
        #pragma unroll
        for (int n = 0; n < 4; ++n) {
            int cw = wcol + n * 16 + lr;
            float bv = bias[cw];
            #pragma unroll
            for (int r = 0; r < 4; ++r) {
                int row = rbase + m * 16 + r;
                dst[(size_t)row * CH + cw] = f2b((acc[m][n][r] + bv) * scale);
            }
        }
}

// proj: A = owin [NT][128], B = projT [128][128]; window-reverse+roll+skip
__global__ __launch_bounds__(256) void k_gproj(const u16* __restrict__ A,
                                               const u16* __restrict__ WT,
                                               const float* __restrict__ bias,
                                               const float* __restrict__ xin,
                                               float* __restrict__ out)
{
    __shared__ __align__(16) char smem[65536];
    GEMM_PROLOGUE
    int row0 = blockIdx.x * 128;
    stage_tile(A + (size_t)row0 * CH, CH * 2, smem, tid);
    stage_tile(WT, CH * 2, smem + 32768, tid);
    __syncthreads();
    compute_ktile(smem, smem + 32768, acc, tid);
    int rbase = row0 + wrow + lk * 4;
    #pragma unroll
    for (int m = 0; m < 4; ++m)
        #pragma unroll
        for (int r = 0; r < 4; ++r) {
            int t = rbase + m * 16 + r;
            int w = t / NN, n2 = t % NN;
            int bb = w >> 6, iw = w & 63;
            int wh = iw >> 3, wwn = iw & 7;
            int i = n2 / 7, j = n2 % 7;
            int dh = (wh * 7 + i + SHIFT) % IMG;
            int dw = (wwn * 7 + j + SHIFT) % IMG;
            size_t drow = ((size_t)bb * 3136 + dh * 56 + dw) * CH;
            #pragma unroll
            for (int n = 0; n < 4; ++n) {
                int cw = wcol + n * 16 + lr;
                out[drow + cw] = xin[drow + cw] + acc[m][n][r] + bias[cw];
            }
        }
}

// ---------------------------------------------------------------
// Fused MLP: out[t] += gelu(ln2[t] @ W1 + b1) @ W2 + b2
// Per block: 128 rows. 4 chunks of 128 fc1-cols (= fc2 K-chunks).
// LDS: A 32KB | W 32KB (W1_c then W2_c) | H 32KB (swizzled, reg->ds_write)
// ---------------------------------------------------------------
__global__ __launch_bounds__(256) void k_mlp(const u16* __restrict__ A_,
                                             const u16* __restrict__ WT1,
                                             const float* __restrict__ b1,
                                             const u16* __restrict__ WT2,
                                             const float* __restrict__ b2,
                                             float* __restrict__ out)
{
    __shared__ __align__(16) char smem[98304];
    char* Abuf = smem;
    char* Wbuf = smem + 32768;
    char* Hbuf = smem + 65536;
    GEMM_PROLOGUE            // acc = fc2 accumulator
    int row0 = blockIdx.x * 128;
    stage_tile(A_ + (size_t)row0 * CH, CH * 2, Abuf, tid);
    for (int c = 0; c < 4; ++c) {
        if (c) __syncthreads();                       // done reading W2_{c-1}
        stage_tile(WT1 + (size_t)c * 128 * CH, CH * 2, Wbuf, tid);
        __syncthreads();                              // A + W1_c ready
        f32x4 acc1[4][4];
        #pragma unroll
        for (int m = 0; m < 4; ++m)
            #pragma unroll
            for (int n = 0; n < 4; ++n)
                acc1[m][n] = (f32x4){0.f, 0.f, 0.f, 0.f};
        compute_ktile(Abuf, Wbuf, acc1, tid);
        __syncthreads();                              // all done reading W1_c
        stage_tile(WT2 + c * 128, MLPD * 2, Wbuf, tid);   // fc2 k-chunk c
        // write H = gelu(acc1 + b1) into Hbuf, swizzled
        #pragma unroll
        for (int m = 0; m < 4; ++m)
            #pragma unroll
            for (int n = 0; n < 4; ++n) {
                int coll = wcol + n * 16 + lr;        // local col 0..127
                float bv = b1[c * 128 + coll];
                #pragma unroll
                for (int r = 0; r < 4; ++r) {
                    int rowl = wrow + m * 16 + lk * 4 + r;  // local row 0..127
                    float v = acc1[m][n][r] + bv;
                    float gv = 0.5f * v * (1.0f + erff(v * 0.70710678118654752f));
                    *(u16*)(Hbuf + rowl * 256 + ((coll * 2) ^ ((rowl & 7) << 4))) = f2b(gv);
                }
            }
        __syncthreads();                              // Hbuf written, W2_c staged
        compute_ktile(Hbuf, Wbuf, acc, tid);          // acc += H_c @ W2_c
    }
    int rbase = row0 + wrow + lk * 4;
    #pragma unroll
    for (int m = 0; m < 4; ++m)
        #pragma unroll
        for (int n = 0; n < 4; ++n) {
            int cw = wcol + n * 16 + lr;
            float bv = b2[cw];
            #pragma unroll
            for (int r = 0; r < 4; ++r) {
                int t = rbase + m * 16 + r;
                size_t o = (size_t)t * CH + cw;
                out[o] = out[o] + acc[m][n][r] + bv;
            }
        }
}

// ---------------------------------------------------------------
// Attention: one block per (window, head). q/k/v layout [w*49+n][head*32+d]
// ---------------------------------------------------------------
__global__ __launch_bounds__(256) void k_attn(const u16* __restrict__ q,
                                              const u16* __restrict__ kk,
                                              const u16* __restrict__ vv,
                                              const float* __restrict__ relt,
                                              u16* __restrict__ owin)
{
    __shared__ float Q[NN][HD], K[NN][HD], V[NN][HD];
    __shared__ float S[NN][NN];
    int w = blockIdx.x >> 2, head = blockIdx.x & 3;
    size_t base = (size_t)w * NN * CH + head * HD;
    int tid = threadIdx.x;
    for (int i = tid; i < NN * HD; i += 256) {
        int n = i >> 5, d = i & 31;
        Q[n][d] = b2f(q[base + (size_t)n * CH + d]);
        K[n][d] = b2f(kk[base + (size_t)n * CH + d]);
        V[n][d] = b2f(vv[base + (size_t)n * CH + d]);
    }
    __syncthreads();
    int iw = w & 63;
    int wh = iw >> 3, ww = iw & 7;
    for (int e = tid; e < NN * NN; e += 256) {
        int n = e / NN, m = e % NN;
        float acc = 0.f;
        #pragma unroll
        for (int d = 0; d < HD; ++d) acc += Q[n][d] * K[m][d];
        int in_ = n / 7, jn = n % 7, im = m / 7, jm = m % 7;
        int ridx = (in_ - im + 6) * 13 + (jn - jm + 6);
        acc += relt[ridx * NHEADS + head];
        int hn = wh * 7 + in_, wn = ww * 7 + jn;
        int hm = wh * 7 + im, wm = ww * 7 + jm;
        int zn = (hn < 49 ? 0 : (hn < 53 ? 1 : 2)) * 3 + (wn < 49 ? 0 : (wn < 53 ? 1 : 2));
        int zm = (hm < 49 ? 0 : (hm < 53 ? 1 : 2)) * 3 + (wm < 49 ? 0 : (wm < 53 ? 1 : 2));
        if (zn != zm) acc -= 100.0f;
        ((float*)S)[e] = acc;
    }
    __syncthreads();
    if (tid < NN) {
        float mx = -1e30f;
        #pragma unroll 7
        for (int m = 0; m < NN; ++m) mx = fmaxf(mx, S[tid][m]);
        float sum = 0.f;
        #pragma unroll 7
        for (int m = 0; m < NN; ++m) { float e_ = __expf(S[tid][m] - mx); S[tid][m] = e_; sum += e_; }
        float inv = 1.0f / sum;
        #pragma unroll 7
        for (int m = 0; m < NN; ++m) S[tid][m] *= inv;
    }
    __syncthreads();
    for (int e = tid; e < NN * HD; e += 256) {
        int n = e >> 5, d = e & 31;
        float acc = 0.f;
        #pragma unroll 7
        for (int m = 0; m < NN; ++m) acc += S[n][m] * V[m][d];
        owin[(size_t)(w * NN + n) * CH + head * HD + d] = f2b(acc);
    }
}

// ---------------------------------------------------------------
extern "C" void kernel_launch(void* const* d_in, const int* in_sizes, int n_in,
                              void* d_out, int out_size, void* d_ws, size_t ws_size,
                              hipStream_t stream) {
    const float* x       = (const float*)d_in[0];
    const float* qkv_w   = (const float*)d_in[1];
    const float* qkv_b   = (const float*)d_in[2];
    const float* proj_w  = (const float*)d_in[3];
    const float* proj_b  = (const float*)d_in[4];
    const float* rel_t   = (const float*)d_in[5];
    const float* n1g     = (const float*)d_in[6];
    const float* n1b     = (const float*)d_in[7];
    const float* n2g     = (const float*)d_in[8];
    const float* n2b     = (const float*)d_in[9];
    const float* fc1_w   = (const float*)d_in[10];
    const float* fc1_b   = (const float*)d_in[11];
    const float* fc2_w   = (const float*)d_in[12];
    const float* fc2_b   = (const float*)d_in[13];
    float* out = (float*)d_out;

    const size_t REG = (size_t)NT * CH;
    u16* U0 = (u16*)d_ws;            // hwin (ln1 out) -> owin (attn out)
    u16* U1 = U0 + REG;              // q -> ln2
    u16* U2 = U1 + REG;              // k
    u16* U3 = U2 + REG;              // v
    u16* wt = U3 + REG;              // 196608 u16 = 384KB of bf16 weights
    u16* wtq  = wt;
    u16* wtp  = wt + 49152;
    u16* wtf1 = wt + 65536;
    u16* wtf2 = wt + 131072;
    u16* hwin = U0;
    u16* qb   = U1;
    u16* kbp  = U2;
    u16* vbp  = U3;
    u16* owin = U0;                  // reuse: hwin dead after k_gqkv
    u16* ln2  = U1;                  // reuse: q dead after k_attn

    k_prep<<<768, 256, 0, stream>>>(qkv_w, proj_w, fc1_w, fc2_w, wt);
    k_ln<<<NT / 4, 256, 0, stream>>>(x, n1g, n1b, hwin, 1);
    k_gqkv<<<784 * 3, 256, 0, stream>>>(hwin, wtq, qkv_b, qb, kbp, vbp);
    k_attn<<<NWIN * NHEADS, 256, 0, stream>>>(qb, kbp, vbp, rel_t, owin);
    k_gproj<<<784, 256, 0, stream>>>(owin, wtp, proj_b, x, out);
    k_ln<<<NT / 4, 256, 0, stream>>>(out, n2g, n2b, ln2, 0);
    k_mlp<<<784, 256, 0, stream>>>(ln2, wtf1, fc1_b, wtf2, fc2_b, out);
}

// Round 9
// 371.383 us; speedup vs baseline: 2.9662x; 1.4869x over previous
//
#include <hip/hip_runtime.h>
#include <hip/hip_bf16.h>
#include <math.h>

#define NT     100352
#define NWIN   2048
#define NN     49
#define CH     128
#define NHEADS 4
#define HD     32
#define MLPD   512
#define SHIFT  3
#define IMG    56
#define SCALE_Q 0.17677669529663687f

typedef unsigned short u16;
typedef unsigned int   u32;
typedef __attribute__((ext_vector_type(8))) short sh8;
typedef __attribute__((ext_vector_type(4))) float f32x4;

__device__ __forceinline__ float b2f(u16 h) {
    u32 u = ((u32)h) << 16;
    return __uint_as_float(u);
}
__device__ __forceinline__ u16 f2b(float f) {
    u32 u = __float_as_uint(f);
    u32 r = (u + 0x7fffu + ((u >> 16) & 1u)) >> 16;
    return (u16)r;
}

// ---------------------------------------------------------------
// weight prep: f32 [K][N] -> bf16 [N][K] (transposed), all 4 mats
// ---------------------------------------------------------------
__global__ __launch_bounds__(256) void k_prep(const float* __restrict__ qkv_w,
                                              const float* __restrict__ proj_w,
                                              const float* __restrict__ fc1_w,
                                              const float* __restrict__ fc2_w,
                                              u16* __restrict__ wt)
{
    int i = blockIdx.x * 256 + threadIdx.x;
    if (i < 49152)       { int n = i >> 7, k = i & 127;             wt[i] = f2b(qkv_w[k * 384 + n]); }
    else if (i < 65536)  { int j = i - 49152; int n = j >> 7, k = j & 127; wt[i] = f2b(proj_w[k * 128 + n]); }
    else if (i < 131072) { int j = i - 65536; int n = j >> 7, k = j & 127; wt[i] = f2b(fc1_w[k * 512 + n]); }
    else                 { int j = i - 131072; int n = j >> 9, k = j & 511; wt[i] = f2b(fc2_w[k * 128 + n]); }
}

// ---------------------------------------------------------------
// bias+mask precompute: bias_full[cls][head][49][49] f32, cls=(wh==7)*2+(ww==7)
// ---------------------------------------------------------------
__global__ __launch_bounds__(256) void k_bias(const float* __restrict__ relt,
                                              float* __restrict__ bo)
{
    int idx = blockIdx.x * 256 + threadIdx.x;
    if (idx >= 4 * 4 * 2401) return;
    int ch = idx / 2401;
    int rc = idx % 2401;
    int row = rc / NN, col = rc % NN;
    int cls = ch >> 2, head = ch & 3;
    int in_ = row / 7, jn = row % 7, im = col / 7, jm = col % 7;
    int ridx = (in_ - im + 6) * 13 + (jn - jm + 6);
    float v = relt[ridx * NHEADS + head];
    int zn_h = (cls & 2) ? (in_ < 4 ? 1 : 2) : 0;
    int zn_w = (cls & 1) ? (jn < 4 ? 1 : 2) : 0;
    int zm_h = (cls & 2) ? (im < 4 ? 1 : 2) : 0;
    int zm_w = (cls & 1) ? (jm < 4 ? 1 : 2) : 0;
    if (zn_h * 3 + zn_w != zm_h * 3 + zm_w) v -= 100.0f;
    bo[idx] = v;
}

// ---------------------------------------------------------------
// LN (+ optional roll & window partition) -> bf16
// ---------------------------------------------------------------
__global__ __launch_bounds__(256) void k_ln(const float* __restrict__ x,
                                            const float* __restrict__ g,
                                            const float* __restrict__ bta,
                                            u16* __restrict__ out, int rolled)
{
    int wave = threadIdx.x >> 6;
    int lane = threadIdx.x & 63;
    int t = blockIdx.x * 4 + wave;
    if (t >= NT) return;
    int src;
    if (rolled) {
        int w = t / NN, n = t % NN;
        int bb = w >> 6, iw = w & 63;
        int wh = iw >> 3, ww = iw & 7;
        int i = n / 7, j = n % 7;
        int hs = (wh * 7 + i + SHIFT) % IMG;
        int wsd = (ww * 7 + j + SHIFT) % IMG;
        src = bb * 3136 + hs * 56 + wsd;
    } else {
        src = t;
    }
    float v0 = x[(size_t)src * CH + lane];
    float v1 = x[(size_t)src * CH + 64 + lane];
    float s = v0 + v1;
    #pragma unroll
    for (int o = 32; o; o >>= 1) s += __shfl_xor(s, o);
    float mu = s * (1.0f / 128.0f);
    float d0 = v0 - mu, d1 = v1 - mu;
    float vs = d0 * d0 + d1 * d1;
    #pragma unroll
    for (int o = 32; o; o >>= 1) vs += __shfl_xor(vs, o);
    float rs = rsqrtf(vs * (1.0f / 128.0f) + 1e-5f);
    out[(size_t)t * CH + lane]      = f2b(d0 * rs * g[lane] + bta[lane]);
    out[(size_t)t * CH + 64 + lane] = f2b(d1 * rs * g[64 + lane] + bta[64 + lane]);
}

// ---------------------------------------------------------------
// MFMA GEMM core: 128x128 tile, BK=128, 4 waves (64x64 each)
// ---------------------------------------------------------------
__device__ __forceinline__ void stage_tile(const u16* g, size_t krow_bytes, char* lds, int tid)
{
    #pragma unroll
    for (int it = 0; it < 8; ++it) {
        int o = (tid + it * 256) * 16;
        int row = o >> 8;
        int wi = (o & 255) ^ ((row & 7) << 4);
        const char* src = (const char*)g + (size_t)row * krow_bytes + wi;
        __builtin_amdgcn_global_load_lds((const __attribute__((address_space(1))) u32*)src,
                                         (__attribute__((address_space(3))) u32*)(lds + o),
                                         16, 0, 0);
    }
}

__device__ __forceinline__ void compute_ktile(const char* pA, const char* pB, f32x4 acc[4][4], int tid)
{
    int lane = tid & 63;
    int wv = tid >> 6;
    int wrow = (wv >> 1) * 64, wcol = (wv & 1) * 64;
    int lr = lane & 15, lk = lane >> 4;
    int xm = (lr & 7) << 4;
    #pragma unroll
    for (int ks = 0; ks < 4; ++ks) {
        int kb = ks * 64 + lk * 16;
        sh8 a[4], b[4];
        #pragma unroll
        for (int m = 0; m < 4; ++m) {
            int ra = wrow + m * 16 + lr;
            a[m] = *(const sh8*)(pA + ra * 256 + (kb ^ xm));
        }
        #pragma unroll
        for (int n = 0; n < 4; ++n) {
            int rb = wcol + n * 16 + lr;
            b[n] = *(const sh8*)(pB + rb * 256 + (kb ^ xm));
        }
        #pragma unroll
        for (int m = 0; m < 4; ++m)
            #pragma unroll
            for (int n = 0; n < 4; ++n)
                acc[m][n] = __builtin_amdgcn_mfma_f32_16x16x32_bf16(a[m], b[n], acc[m][n], 0, 0, 0);
    }
}

#define GEMM_PROLOGUE                                           \
    int tid = threadIdx.x;                                      \
    int lane = tid & 63, wv = tid >> 6;                         \
    int wrow = (wv >> 1) * 64, wcol = (wv & 1) * 64;            \
    int lr = lane & 15, lk = lane >> 4;                         \
    f32x4 acc[4][4];                                            \
    _Pragma("unroll")                                           \
    for (int m = 0; m < 4; ++m)                                 \
        _Pragma("unroll")                                       \
        for (int n = 0; n < 4; ++n)                             \
            acc[m][n] = (f32x4){0.f, 0.f, 0.f, 0.f};

// qkv GEMM
__global__ __launch_bounds__(256) void k_gqkv(const u16* __restrict__ A,
                                              const u16* __restrict__ WT,
                                              const float* __restrict__ bias_all,
                                              u16* __restrict__ qb,
                                              u16* __restrict__ kb,
                                              u16* __restrict__ vb)
{
    __shared__ __align__(16) char smem[65536];
    GEMM_PROLOGUE
    int mt = blockIdx.x / 3, nt = blockIdx.x % 3;
    int row0 = mt * 128;
    stage_tile(A + (size_t)row0 * CH, CH * 2, smem, tid);
    stage_tile(WT + (size_t)nt * 128 * CH, CH * 2, smem + 32768, tid);
    __syncthreads();
    compute_ktile(smem, smem + 32768, acc, tid);
    const float* bias = bias_all + nt * 128;
    u16* dst = nt == 0 ? qb : (nt == 1 ? kb : vb);
    float scale = nt == 0 ? SCALE_Q : 1.0f;
    int rbase = row0 + wrow + lk * 4;
    #pragma unroll
    for (int m = 0; m < 4; ++m)
        #pragma unroll
        for (int n = 0; n < 4; ++n) {
            int cw = wcol + n * 16 + lr;
            float bv = bias[cw];
            #pragma unroll
            for (int r = 0; r < 4; ++r) {
                int row = rbase + m * 16 + r;
                dst[(size_t)row * CH + cw] = f2b((acc[m][n][r] + bv) * scale);
            }
        }
}

// proj GEMM + window-reverse + roll + skip
__global__ __launch_bounds__(256) void k_gproj(const u16* __restrict__ A,
                                               const u16* __restrict__ WT,
                                               const float* __restrict__ bias,
                                               const float* __restrict__ xin,
                                               float* __restrict__ out)
{
    __shared__ __align__(16) char smem[65536];
    GEMM_PROLOGUE
    int row0 = blockIdx.x * 128;
    stage_tile(A + (size_t)row0 * CH, CH * 2, smem, tid);
    stage_tile(WT, CH * 2, smem + 32768, tid);
    __syncthreads();
    compute_ktile(smem, smem + 32768, acc, tid);
    int rbase = row0 + wrow + lk * 4;
    #pragma unroll
    for (int m = 0; m < 4; ++m)
        #pragma unroll
        for (int r = 0; r < 4; ++r) {
            int t = rbase + m * 16 + r;
            int w = t / NN, n2 = t % NN;
            int bb = w >> 6, iw = w & 63;
            int wh = iw >> 3, wwn = iw & 7;
            int i = n2 / 7, j = n2 % 7;
            int dh = (wh * 7 + i + SHIFT) % IMG;
            int dw = (wwn * 7 + j + SHIFT) % IMG;
            size_t drow = ((size_t)bb * 3136 + dh * 56 + dw) * CH;
            #pragma unroll
            for (int n = 0; n < 4; ++n) {
                int cw = wcol + n * 16 + lr;
                out[drow + cw] = xin[drow + cw] + acc[m][n][r] + bias[cw];
            }
        }
}

// fused MLP
__global__ __launch_bounds__(256) void k_mlp(const u16* __restrict__ A_,
                                             const u16* __restrict__ WT1,
                                             const float* __restrict__ b1,
                                             const u16* __restrict__ WT2,
                                             const float* __restrict__ b2,
                                             float* __restrict__ out)
{
    __shared__ __align__(16) char smem[98304];
    char* Abuf = smem;
    char* Wbuf = smem + 32768;
    char* Hbuf = smem + 65536;
    GEMM_PROLOGUE
    int row0 = blockIdx.x * 128;
    stage_tile(A_ + (size_t)row0 * CH, CH * 2, Abuf, tid);
    for (int c = 0; c < 4; ++c) {
        if (c) __syncthreads();
        stage_tile(WT1 + (size_t)c * 128 * CH, CH * 2, Wbuf, tid);
        __syncthreads();
        f32x4 acc1[4][4];
        #pragma unroll
        for (int m = 0; m < 4; ++m)
            #pragma unroll
            for (int n = 0; n < 4; ++n)
                acc1[m][n] = (f32x4){0.f, 0.f, 0.f, 0.f};
        compute_ktile(Abuf, Wbuf, acc1, tid);
        __syncthreads();
        stage_tile(WT2 + c * 128, MLPD * 2, Wbuf, tid);
        #pragma unroll
        for (int m = 0; m < 4; ++m)
            #pragma unroll
            for (int n = 0; n < 4; ++n) {
                int coll = wcol + n * 16 + lr;
                float bv = b1[c * 128 + coll];
                #pragma unroll
                for (int r = 0; r < 4; ++r) {
                    int rowl = wrow + m * 16 + lk * 4 + r;
                    float v = acc1[m][n][r] + bv;
                    float gv = 0.5f * v * (1.0f + erff(v * 0.70710678118654752f));
                    *(u16*)(Hbuf + rowl * 256 + ((coll * 2) ^ ((rowl & 7) << 4))) = f2b(gv);
                }
            }
        __syncthreads();
        compute_ktile(Hbuf, Wbuf, acc, tid);
    }
    int rbase = row0 + wrow + lk * 4;
    #pragma unroll
    for (int m = 0; m < 4; ++m)
        #pragma unroll
        for (int n = 0; n < 4; ++n) {
            int cw = wcol + n * 16 + lr;
            float bv = b2[cw];
            #pragma unroll
            for (int r = 0; r < 4; ++r) {
                int t = rbase + m * 16 + r;
                size_t o = (size_t)t * CH + cw;
                out[o] = out[o] + acc[m][n][r] + bv;
            }
        }
}

// ---------------------------------------------------------------
// MFMA attention: one block per window, one wave per head.
// Q,K fragments direct from global ([tok][128] layout == fragment layout).
// V transposed into LDS [32][72]; P in LDS [64][72]; pad tokens 49..63.
// ---------------------------------------------------------------
__global__ __launch_bounds__(256) void k_attn2(const u16* __restrict__ q,
                                               const u16* __restrict__ kk,
                                               const u16* __restrict__ vv,
                                               const float* __restrict__ biasf,
                                               u16* __restrict__ owin)
{
    __shared__ __align__(16) char lds[55296];
    int w = blockIdx.x;
    int tid = threadIdx.x;
    int lane = tid & 63;
    int head = tid >> 6;
    char* Vt = lds + head * 4608;            // [32][72] u16, stride 144B
    char* P  = lds + 18432 + head * 9216;    // [64][72] u16, stride 144B
    int lr = lane & 15, lk = lane >> 4;
    size_t tbase = (size_t)w * NN * CH + head * HD;

    // stage V transposed (zero-fill pad rows 49..63)
    {
        int s = lane;
        u16 vrow[32];
        if (s < NN) {
            const u16* src = vv + tbase + (size_t)s * CH;
            #pragma unroll
            for (int c = 0; c < 4; ++c) {
                sh8 v8 = *(const sh8*)(src + c * 8);
                #pragma unroll
                for (int e = 0; e < 8; ++e) vrow[c * 8 + e] = (u16)v8[e];
            }
        } else {
            #pragma unroll
            for (int d = 0; d < 32; ++d) vrow[d] = 0;
        }
        #pragma unroll
        for (int d = 0; d < 32; ++d)
            *(u16*)(Vt + d * 144 + s * 2) = vrow[d];
    }

    // QK^T: 16 MFMA, K=32 (one k-step). frags straight from global.
    f32x4 acc[4][4];
    #pragma unroll
    for (int m = 0; m < 4; ++m)
        #pragma unroll
        for (int n = 0; n < 4; ++n)
            acc[m][n] = (f32x4){0.f, 0.f, 0.f, 0.f};
    {
        sh8 afr[4], bfr[4];
        #pragma unroll
        for (int m = 0; m < 4; ++m)
            afr[m] = *(const sh8*)(q + tbase + (size_t)(m * 16 + lr) * CH + lk * 8);
        #pragma unroll
        for (int n = 0; n < 4; ++n)
            bfr[n] = *(const sh8*)(kk + tbase + (size_t)(n * 16 + lr) * CH + lk * 8);
        #pragma unroll
        for (int m = 0; m < 4; ++m)
            #pragma unroll
            for (int n = 0; n < 4; ++n)
                acc[m][n] = __builtin_amdgcn_mfma_f32_16x16x32_bf16(afr[m], bfr[n], acc[m][n], 0, 0, 0);
    }

    // bias + mask + row softmax (rows live in 16-lane groups) -> P bf16
    int iw = w & 63;
    int wh = iw >> 3, ww = iw & 7;
    const float* bf = biasf + (size_t)((((wh == 7) ? 2 : 0) + ((ww == 7) ? 1 : 0)) * 4 + head) * 2401;
    #pragma unroll
    for (int m = 0; m < 4; ++m) {
        #pragma unroll
        for (int r = 0; r < 4; ++r) {
            int row = m * 16 + lk * 4 + r;
            float sv[4];
            #pragma unroll
            for (int n = 0; n < 4; ++n) {
                int col = n * 16 + lr;
                float v = acc[m][n][r];
                if (col < NN) {
                    if (row < NN) v += bf[row * NN + col];
                } else {
                    v = -1e30f;
                }
                sv[n] = v;
            }
            float mx = fmaxf(fmaxf(sv[0], sv[1]), fmaxf(sv[2], sv[3]));
            #pragma unroll
            for (int o = 1; o < 16; o <<= 1) mx = fmaxf(mx, __shfl_xor(mx, o));
            float e0 = __expf(sv[0] - mx), e1 = __expf(sv[1] - mx);
            float e2 = __expf(sv[2] - mx), e3 = __expf(sv[3] - mx);
            float sum = e0 + e1 + e2 + e3;
            #pragma unroll
            for (int o = 1; o < 16; o <<= 1) sum += __shfl_xor(sum, o);
            float inv = 1.0f / sum;
            *(u16*)(P + row * 144 + (0 * 16 + lr) * 2) = f2b(e0 * inv);
            *(u16*)(P + row * 144 + (1 * 16 + lr) * 2) = f2b(e1 * inv);
            *(u16*)(P + row * 144 + (2 * 16 + lr) * 2) = f2b(e2 * inv);
            *(u16*)(P + row * 144 + (3 * 16 + lr) * 2) = f2b(e3 * inv);
        }
    }
    __syncthreads();

    // PV: O[64][32] = P[64][64] @ V[64][32], 16 MFMA (2 k-steps x 4m x 2n)
    f32x4 oacc[4][2];
    #pragma unroll
    for (int m = 0; m < 4; ++m)
        #pragma unroll
        for (int n = 0; n < 2; ++n)
            oacc[m][n] = (f32x4){0.f, 0.f, 0.f, 0.f};
    #pragma unroll
    for (int s0 = 0; s0 < 2; ++s0) {
        sh8 pa[4], vbf[2];
        #pragma unroll
        for (int m = 0; m < 4; ++m)
            pa[m] = *(const sh8*)(P + (m * 16 + lr) * 144 + (s0 * 32 + lk * 8) * 2);
        #pragma unroll
        for (int n = 0; n < 2; ++n)
            vbf[n] = *(const sh8*)(Vt + (n * 16 + lr) * 144 + (s0 * 32 + lk * 8) * 2);
        #pragma unroll
        for (int m = 0; m < 4; ++m)
            #pragma unroll
            for (int n = 0; n < 2; ++n)
                oacc[m][n] = __builtin_amdgcn_mfma_f32_16x16x32_bf16(pa[m], vbf[n], oacc[m][n], 0, 0, 0);
    }
    #pragma unroll
    for (int m = 0; m < 4; ++m)
        #pragma unroll
        for (int n = 0; n < 2; ++n)
            #pragma unroll
            for (int r = 0; r < 4; ++r) {
                int row = m * 16 + lk * 4 + r;
                if (row < NN)
                    owin[(size_t)(w * NN + row) * CH + head * HD + n * 16 + lr] = f2b(oacc[m][n][r]);
            }
}

// ---------------------------------------------------------------
extern "C" void kernel_launch(void* const* d_in, const int* in_sizes, int n_in,
                              void* d_out, int out_size, void* d_ws, size_t ws_size,
                              hipStream_t stream) {
    const float* x       = (const float*)d_in[0];
    const float* qkv_w   = (const float*)d_in[1];
    const float* qkv_b   = (const float*)d_in[2];
    const float* proj_w  = (const float*)d_in[3];
    const float* proj_b  = (const float*)d_in[4];
    const float* rel_t   = (const float*)d_in[5];
    const float* n1g     = (const float*)d_in[6];
    const float* n1b     = (const float*)d_in[7];
    const float* n2g     = (const float*)d_in[8];
    const float* n2b     = (const float*)d_in[9];
    const float* fc1_w   = (const float*)d_in[10];
    const float* fc1_b   = (const float*)d_in[11];
    const float* fc2_w   = (const float*)d_in[12];
    const float* fc2_b   = (const float*)d_in[13];
    float* out = (float*)d_out;

    const size_t REG = (size_t)NT * CH;
    u16* U0 = (u16*)d_ws;            // hwin -> owin
    u16* U1 = U0 + REG;              // q -> ln2
    u16* U2 = U1 + REG;              // k
    u16* U3 = U2 + REG;              // v
    u16* wt = U3 + REG;              // 196608 u16 of bf16 weights
    u16* wtq  = wt;
    u16* wtp  = wt + 49152;
    u16* wtf1 = wt + 65536;
    u16* wtf2 = wt + 131072;
    float* biasf = (float*)(wt + 196608);   // 38416 f32 = 150KB
    u16* hwin = U0;
    u16* qb   = U1;
    u16* kbp  = U2;
    u16* vbp  = U3;
    u16* owin = U0;
    u16* ln2  = U1;

    k_prep<<<768, 256, 0, stream>>>(qkv_w, proj_w, fc1_w, fc2_w, wt);
    k_bias<<<151, 256, 0, stream>>>(rel_t, biasf);
    k_ln<<<NT / 4, 256, 0, stream>>>(x, n1g, n1b, hwin, 1);
    k_gqkv<<<784 * 3, 256, 0, stream>>>(hwin, wtq, qkv_b, qb, kbp, vbp);
    k_attn2<<<NWIN, 256, 0, stream>>>(qb, kbp, vbp, biasf, owin);
    k_gproj<<<784, 256, 0, stream>>>(owin, wtp, proj_b, x, out);
    k_ln<<<NT / 4, 256, 0, stream>>>(out, n2g, n2b, ln2, 0);
    k_mlp<<<784, 256, 0, stream>>>(ln2, wtf1, fc1_b, wtf2, fc2_b, out);
}